// Round 11
// baseline (202.251 us; speedup 1.0000x reference)
//
#include <hip/hip_runtime.h>

typedef unsigned short u16;
typedef unsigned char u8;
typedef __attribute__((ext_vector_type(8))) short s8v;
typedef __attribute__((ext_vector_type(4))) float f4v;
typedef __attribute__((ext_vector_type(2))) long l2v;

enum { MODE_SCALE = 2, MODE_FINAL = 3 };

__device__ __forceinline__ u16 f2bf(float f) {
  unsigned u = __builtin_bit_cast(unsigned, f);
  u += 0x7fffu + ((u >> 16) & 1u);
  return (u16)(u >> 16);
}
__device__ __forceinline__ float bf2f(u16 h) {
  unsigned u = ((unsigned)h) << 16;
  return __builtin_bit_cast(float, u);
}
__device__ __forceinline__ void gload16(const void* g, void* l) {
  __builtin_amdgcn_global_load_lds(
      (const __attribute__((address_space(1))) unsigned int*)g,
      (__attribute__((address_space(3))) unsigned int*)l, 16, 0, 0);
}
__device__ __forceinline__ unsigned pk4fp8(float a, float b, float c, float d) {
  int lo = __builtin_amdgcn_cvt_pk_fp8_f32(a, b, 0, false);
  return (unsigned)__builtin_amdgcn_cvt_pk_fp8_f32(c, d, lo, true);
}
__device__ __forceinline__ u8 f2fp8(float a) {
  return (u8)(__builtin_amdgcn_cvt_pk_fp8_f32(a, a, 0, false) & 0xff);
}
// k-interleave permutation within each aligned 64B k-group: byte j ->
// ((j>>3)&3)*16 + ((j>>5)&1)*8 + (j&7).  Chunk q (16B) of a row then holds
// [k 8q..8q+7][k 32+8q..32+8q+7] = both MFMA k-slices for lane quad q.
// 4-aligned 4B blocks map to contiguous 4B (j&7 preserved).
__device__ __forceinline__ int kperm(int j) {
  return (j & ~63) | (((j >> 3) & 3) << 4) | (((j >> 5) & 1) << 3) | (j & 7);
}

// ------- prep fat kernel: gn partial stats + weight casts + zeroing -------
// blocks [0,512):    gn_stats (x partial sums, 2 channels/block)
// blocks [512,1536): wq/wk/wv -> fp8 k-ilv (w8); wo -> bf16 (wob)
// blocks [1536,1540): zero rowsum (2x4096 f32)
__global__ __launch_bounds__(256) void prep(
    const float* __restrict__ x, const float* __restrict__ w0,
    const float* __restrict__ w1, const float* __restrict__ w2,
    const float* __restrict__ w3, float2* __restrict__ part,
    u16* __restrict__ wob, u8* __restrict__ w8,
    float* __restrict__ rowsum) {
  const int bid = blockIdx.x;
  const int t = threadIdx.x;
  if (bid < 512) {
    const float4* p4 = (const float4*)(x + (long)bid * 8192);
    float s = 0.f, q = 0.f;
#pragma unroll
    for (int j = 0; j < 8; ++j) {
      float4 f = p4[t + 256 * j];
      s += f.x + f.y + f.z + f.w;
      q += f.x * f.x + f.y * f.y + f.z * f.z + f.w * f.w;
    }
#pragma unroll
    for (int o = 32; o; o >>= 1) {
      s += __shfl_xor(s, o, 64);
      q += __shfl_xor(q, o, 64);
    }
    __shared__ float rs[4], rq[4];
    int lane = t & 63, wv = t >> 6;
    if (lane == 0) { rs[wv] = s; rq[wv] = q; }
    __syncthreads();
    if (t == 0)
      part[bid] = make_float2(rs[0] + rs[1] + rs[2] + rs[3],
                              rq[0] + rq[1] + rq[2] + rq[3]);
  } else if (bid < 1536) {
    int wb = bid - 512;
    int which = wb >> 8;
    const float* w = which == 0 ? w0 : which == 1 ? w1 : which == 2 ? w2 : w3;
    int i = ((wb & 255) * 256 + t) * 4;
    float4 f = *(const float4*)(w + i);
    if (which == 3) {
      ushort4 r;
      r.x = f2bf(f.x); r.y = f2bf(f.y); r.z = f2bf(f.z); r.w = f2bf(f.w);
      *(ushort4*)(wob + i) = r;
    } else {
      // fp8 k-interleaved on the in-channel (col) axis
      *(unsigned*)(w8 + which * 262144 + (i & ~511) + kperm(i & 511)) =
          pk4fp8(f.x, f.y, f.z, f.w);
    }
  } else {
    int idx = (bid - 1536) * 256 + t;
    float4 z = {0.f, 0.f, 0.f, 0.f};
    *(float4*)(rowsum + idx * 8) = z;
    *(float4*)(rowsum + idx * 8 + 4) = z;
  }
}

// ------- apply groupnorm + transpose -> hn8 fp8 (k-interleaved chans) -----
__global__ __launch_bounds__(256) void gn_apply_t(const float* __restrict__ x,
                                                  const float2* __restrict__ part,
                                                  const float* __restrict__ gamma,
                                                  const float* __restrict__ beta,
                                                  u8* __restrict__ hn8) {
  int p0 = blockIdx.x * 32, c0 = blockIdx.y * 32, b = blockIdx.z;
  __shared__ float tile[32][33];
  __shared__ float2 ABs[32];
  int t = threadIdx.x;
  if (t < 32) {
    int c = c0 + t;
    int g = (b * 512 + c) >> 4;  // global 16-channel group
    float s = 0.f, q = 0.f;
#pragma unroll
    for (int j = 0; j < 8; ++j) {
      float2 pp = part[g * 8 + j];
      s += pp.x; q += pp.y;
    }
    float mean = s * (1.0f / 65536.0f);
    float var = q * (1.0f / 65536.0f) - mean * mean;
    float a = gamma[c] * rsqrtf(var + 1e-6f);
    ABs[t] = make_float2(a, beta[c] - mean * a);
  }
  const float* xb = x + (long)b * 2097152;
#pragma unroll
  for (int j = 0; j < 4; ++j) {
    int lc = (t >> 5) + j * 8, lp = t & 31;
    tile[lc][lp] = xb[(long)(c0 + lc) * 4096 + p0 + lp];
  }
  __syncthreads();
#pragma unroll
  for (int j = 0; j < 4; ++j) {
    int lp = (t >> 5) + j * 8, lc = t & 31;
    float2 ab = ABs[lc];
    float val = tile[lc][lp] * ab.x + ab.y;
    hn8[(long)b * 2097152 + (long)(p0 + lp) * 512 + kperm(c0 + lc)] =
        f2fp8(val);
  }
}

// ------- split-K4 reduce + rowsum normalize -> out_t (bf16) ---------------
__global__ __launch_bounds__(256) void reduce_pv4(const u16* __restrict__ parts,
                                                  u16* __restrict__ out,
                                                  const float* __restrict__ rowsum) {
  long i = ((long)blockIdx.x * 256 + threadIdx.x) * 8;  // [0, 4194304)
  long b = i >> 21, off = i & 2097151;
  const u16* base = parts + b * 8388608 + off;
  float inv = 1.0f / rowsum[b * 4096 + (off >> 9)];
  s8v a = *(const s8v*)(base);
  s8v bb = *(const s8v*)(base + 2097152);
  s8v c = *(const s8v*)(base + 4194304);
  s8v d = *(const s8v*)(base + 6291456);
  s8v o;
#pragma unroll
  for (int j = 0; j < 8; ++j)
    o[j] = (short)f2bf((bf2f((u16)a[j]) + bf2f((u16)bb[j]) + bf2f((u16)c[j]) +
                        bf2f((u16)d[j])) * inv);
  *(s8v*)(out + i) = o;
}

// ------- fused QKV GEMM, all-fp8 (hn8 . w8^T), 256x128 1-barrier loop -----
__global__ __launch_bounds__(512, 4) void gemm_qkv8(
    const u8* __restrict__ hn8, const u8* __restrict__ w8,
    u8* __restrict__ q8, u8* __restrict__ k8, u8* __restrict__ v8,
    const float* __restrict__ bq, const float* __restrict__ bk,
    const float* __restrict__ bv) {
  constexpr int NKT = 8;
  constexpr long ld = 512;
  constexpr long ha = 128 * ld;
  constexpr int BUF = 24576;
  __shared__ __align__(16) u8 lds[73728];

  const int t = threadIdx.x;
  const int lane = t & 63, wv = t >> 6;
  const int wm = wv >> 1, wn = wv & 1;

  int lin = blockIdx.x;
  int xcd = lin & 7, s = lin >> 3;          // s in [0,48)
  int bn_i = s % 12, rest = s / 12;         // rest in [0,4)
  int bm_i = (rest & 1) * 8 + xcd;
  int b = rest >> 1;
  const int bm = bm_i * 256, bn = bn_i * 128;

  const u8* A = hn8 + (long)b * 2097152;
  const int tchunk = ((t & 3) ^ ((t >> 3) & 3)) * 16;
  const u8* pA0 = A + (long)(bm + (t >> 2)) * ld + tchunk;
  const u8* pB0 = w8 + (long)(bn + (t >> 2)) * ld + tchunk;

  const int r16 = lane & 15, q = lane >> 4;
  const int swz = (r16 >> 1) & 3;
  const int caq = (q ^ swz) * 16;
  const int aRow = (wm * 64 + r16) * 64;
  const int bRow = 16384 + (wn * 64 + r16) * 64;

  f4v acc[4][4];
#pragma unroll
  for (int i = 0; i < 4; ++i)
#pragma unroll
    for (int j = 0; j < 4; ++j) acc[i][j] = (f4v){0.f, 0.f, 0.f, 0.f};

#pragma unroll
  for (int T = 0; T < 2; ++T) {
    gload16(pA0 + T * 64, &lds[T * BUF + t * 16]);
    gload16(pA0 + ha + T * 64, &lds[T * BUF + 8192 + t * 16]);
    gload16(pB0 + T * 64, &lds[T * BUF + 16384 + t * 16]);
  }
  asm volatile("s_waitcnt vmcnt(3)" ::: "memory");
  asm volatile("s_barrier" ::: "memory");

  int cur = 0, nbuf = 2;
  const u8* pA = pA0 + 128;
  const u8* pB = pB0 + 128;
  for (int kt = 0; kt < NKT; ++kt) {
    const u8* LA = &lds[cur * BUF];
    u8* SB = &lds[nbuf * BUF];
    const bool st = kt <= NKT - 3;

    l2v af[4], bfv[4];
#pragma unroll
    for (int mi = 0; mi < 4; ++mi)
      af[mi] = *(const l2v*)(LA + aRow + mi * 1024 + caq);
#pragma unroll
    for (int ni = 0; ni < 4; ++ni)
      bfv[ni] = *(const l2v*)(LA + bRow + ni * 1024 + caq);

    if (st) gload16(pA, SB + t * 16);
    __builtin_amdgcn_s_setprio(1);
#pragma unroll
    for (int mi = 0; mi < 2; ++mi)
#pragma unroll
      for (int ni = 0; ni < 4; ++ni) {
        acc[mi][ni] = __builtin_amdgcn_mfma_f32_16x16x32_fp8_fp8(
            af[mi][0], bfv[ni][0], acc[mi][ni], 0, 0, 0);
        acc[mi][ni] = __builtin_amdgcn_mfma_f32_16x16x32_fp8_fp8(
            af[mi][1], bfv[ni][1], acc[mi][ni], 0, 0, 0);
      }
    __builtin_amdgcn_s_setprio(0);
    if (st) gload16(pA + ha, SB + 8192 + t * 16);
    __builtin_amdgcn_s_setprio(1);
#pragma unroll
    for (int mi = 2; mi < 4; ++mi)
#pragma unroll
      for (int ni = 0; ni < 4; ++ni) {
        acc[mi][ni] = __builtin_amdgcn_mfma_f32_16x16x32_fp8_fp8(
            af[mi][0], bfv[ni][0], acc[mi][ni], 0, 0, 0);
        acc[mi][ni] = __builtin_amdgcn_mfma_f32_16x16x32_fp8_fp8(
            af[mi][1], bfv[ni][1], acc[mi][ni], 0, 0, 0);
      }
    __builtin_amdgcn_s_setprio(0);
    if (st) gload16(pB, SB + 16384 + t * 16);

    if (kt < NKT - 1) {
      if (st)
        asm volatile("s_waitcnt vmcnt(3)" ::: "memory");
      else
        asm volatile("s_waitcnt vmcnt(0)" ::: "memory");
      asm volatile("s_barrier" ::: "memory");
    }
    pA += 64;
    pB += 64;
    cur = cur == 2 ? 0 : cur + 1;
    nbuf = nbuf == 2 ? 0 : nbuf + 1;
  }

  const int w = bn >> 9;  // block-uniform: 128-tile within one 512 window
  const float* bias = w == 0 ? bq : w == 1 ? bk : bv;
  u8* qkdst = (w == 0 ? q8 : k8) + (long)b * 2097152;
  u8* vdst = v8 + (long)b * 2097152;
#pragma unroll
  for (int mi = 0; mi < 4; ++mi) {
    int m0 = bm + wm * 64 + mi * 16 + q * 4;
#pragma unroll
    for (int ni = 0; ni < 4; ++ni) {
      int n = bn + wn * 64 + ni * 16 + r16;
      int o = n & 511;
      f4v vvv = acc[mi][ni];
      float bsv = bias[o];
      if (w == 2) {
        // v8[o][m]: pixel axis kperm'd (PV's K); m0%8 in {0,4}
        *(unsigned*)&vdst[(long)o * 4096 + kperm(m0)] =
            pk4fp8(vvv[0] + bsv, vvv[1] + bsv, vvv[2] + bsv, vvv[3] + bsv);
      } else {
        int op = kperm(o);
#pragma unroll
        for (int r2 = 0; r2 < 4; ++r2)
          qkdst[(long)(m0 + r2) * 512 + op] = f2fp8(vvv[r2] + bsv);
      }
    }
  }
}

// ------ fp8 256x256-tile GEMM, 4-phase/K-tile (r1 skeleton + k-ilv) -------
// GM==0: P8 = exp(scale*q8.k8^T - 1) fp8 k-ilv + rowsum atomics.
//        M=N=4096 K=512.                              grid 512, 512 thr
// GM==1: parts = P8 . v8^T (unnormalized, split-K4)   grid 256, 512 thr
// 256x256 tile, BK=64, 8 waves 2Mx4N (wave 128x64), 3 LDS bufs of 32KB.
// Sync skeleton = r1 (correctness-proven): per K-tile 4 phases, each
// {frag ds_reads ; 1 staging gload (kt+2) ; barrier ; lgkmcnt(0) ;
//  setprio(1) 16 MFMA setprio(0) ; barrier}; counted vmcnt(3) before the
// last phase (never 0 mid-loop).  Fragment reads are the k-ilv b128
// conflict-free form (T2) — r1 had 3.08M b64 conflicts; T2 pays on the
// phased structure per the gate table (null on the flat 1-barrier loop).
template <int GM>
__global__ __launch_bounds__(512, 2) void gemm8p(const u8* __restrict__ Ag,
                                                 const u8* __restrict__ Bg,
                                                 u16* __restrict__ Dg,
                                                 float* __restrict__ rowsum) {
  constexpr int NKT = GM == 0 ? 8 : 16;
  constexpr long ld = GM == 0 ? 512 : 4096;  // A and B K-stride (bytes)
  constexpr int nx = GM == 0 ? 16 : 2;       // N tiles (256-wide)
  constexpr long ha = 128 * ld;              // half-tile (128 rows) offset
  constexpr int BUF = 32768;
  __shared__ __align__(16) u8 lds[98304];

  const int t = threadIdx.x;
  const int lane = t & 63, wv = t >> 6;
  const int wm = wv >> 2, wn = wv & 3;

  int lin = blockIdx.x;
  int xcd = lin & 7, s = lin >> 3;
  int bn_i = s % nx, rest = s / nx;
  int bm_i = (rest & 1) * 8 + xcd, rest2 = rest >> 1;
  int ks = 0, b;
  if constexpr (GM == 1) {
    ks = rest2 & 3;
    b = rest2 >> 2;
  } else {
    b = rest2;
  }
  const int bm = bm_i * 256, bn = bn_i * 256;

  const u8* A = Ag + (long)b * (GM == 0 ? 2097152 : 16777216);
  const u8* B = Bg + (long)b * 2097152;
  const long k0 = GM == 1 ? (long)ks * 1024 : 0;

  // staging: thread t covers row (t>>2) of a 128-row half, chunk (t&3);
  // source chunk pre-swizzled so LDS holds row[chunk ^ ((row>>1)&3)].
  const int tchunk = ((t & 3) ^ ((t >> 3) & 3)) * 16;
  const u8* pA0 = A + (long)(bm + (t >> 2)) * ld + k0 + tchunk;
  const u8* pB0 = B + (long)(bn + (t >> 2)) * ld + k0 + tchunk;

  // per-lane read constants: fragment row = lane&15, chunk = lane>>4
  const int r16 = lane & 15, q = lane >> 4;
  const int swz = (r16 >> 1) & 3;
  const int caq = (q ^ swz) * 16;
  const int aRow = (wm * 128 + r16) * 64;          // A zone [0,16384)
  const int bRow = 16384 + (wn * 64 + r16) * 64;   // B zone [16384,32768)

  f4v acc[8][4];
#pragma unroll
  for (int i = 0; i < 8; ++i)
#pragma unroll
    for (int j = 0; j < 4; ++j) acc[i][j] = (f4v){0.f, 0.f, 0.f, 0.f};

  // prologue: stage K-tiles 0,1 into bufs 0,1 (8 loads/thread)
#pragma unroll
  for (int T = 0; T < 2; ++T) {
    gload16(pA0 + T * 64, &lds[T * BUF + t * 16]);
    gload16(pA0 + ha + T * 64, &lds[T * BUF + 8192 + t * 16]);
    gload16(pB0 + T * 64, &lds[T * BUF + 16384 + t * 16]);
    gload16(pB0 + ha + T * 64, &lds[T * BUF + 24576 + t * 16]);
  }
  asm volatile("s_waitcnt vmcnt(4)" ::: "memory");  // tile 0 landed
  asm volatile("s_barrier" ::: "memory");

  int cur = 0, nbuf = 2;
  const u8* pA = pA0 + 128;  // tile kt+2 source
  const u8* pB = pB0 + 128;
  for (int kt = 0; kt < NKT; ++kt) {
    const u8* LA = &lds[cur * BUF];
    u8* SB = &lds[nbuf * BUF];
    const bool st = kt <= NKT - 3;
    l2v a0[4], a1[4], b0[2], b1[2];

#define DS_A(AR, MH)                                                        \
  _Pragma("unroll") for (int mi = 0; mi < 4; ++mi)                          \
      AR[mi] = *(const l2v*)(LA + aRow + ((MH)*4 + mi) * 1024 + caq);
#define DS_B(BR, NH)                                                        \
  _Pragma("unroll") for (int ni = 0; ni < 2; ++ni)                          \
      BR[ni] = *(const l2v*)(LA + bRow + ((NH)*2 + ni) * 1024 + caq);
#define MM(AR, BR, MH, NH)                                                  \
  asm volatile("s_barrier" ::: "memory");                                   \
  asm volatile("s_waitcnt lgkmcnt(0)" ::: "memory");                        \
  __builtin_amdgcn_sched_barrier(0);                                        \
  __builtin_amdgcn_s_setprio(1);                                            \
  _Pragma("unroll") for (int mi = 0; mi < 4; ++mi)                          \
      _Pragma("unroll") for (int ni = 0; ni < 2; ++ni) {                    \
    acc[(MH)*4 + mi][(NH)*2 + ni] =                                         \
        __builtin_amdgcn_mfma_f32_16x16x32_fp8_fp8(                         \
            AR[mi][0], BR[ni][0], acc[(MH)*4 + mi][(NH)*2 + ni], 0, 0, 0);  \
    acc[(MH)*4 + mi][(NH)*2 + ni] =                                         \
        __builtin_amdgcn_mfma_f32_16x16x32_fp8_fp8(                         \
            AR[mi][1], BR[ni][1], acc[(MH)*4 + mi][(NH)*2 + ni], 0, 0, 0);  \
  }                                                                         \
  __builtin_amdgcn_s_setprio(0);                                            \
  __builtin_amdgcn_sched_barrier(0);                                        \
  asm volatile("s_barrier" ::: "memory");

    // phase 0: quadrant (0,0); stage tile kt+2 A-lo
    DS_A(a0, 0)
    DS_B(b0, 0)
    if (st) gload16(pA, SB + t * 16);
    MM(a0, b0, 0, 0)
    // phase 1: (0,1); stage A-hi
    DS_B(b1, 1)
    if (st) gload16(pA + ha, SB + 8192 + t * 16);
    MM(a0, b1, 0, 1)
    // phase 2: (1,0); stage B-lo
    DS_A(a1, 1)
    if (st) gload16(pB, SB + 16384 + t * 16);
    MM(a1, b0, 1, 0)
    // phase 3: (1,1); counted gate for tile kt+1, then stage B-hi
    if (kt < NKT - 1) {
      if (kt < NKT - 2)
        asm volatile("s_waitcnt vmcnt(3)" ::: "memory");
      else
        asm volatile("s_waitcnt vmcnt(0)" ::: "memory");
    }
    if (st) gload16(pB + ha, SB + 24576 + t * 16);
    MM(a1, b1, 1, 1)

#undef DS_A
#undef DS_B
#undef MM

    pA += 64;
    pB += 64;
    cur = cur == 2 ? 0 : cur + 1;
    nbuf = nbuf == 2 ? 0 : nbuf + 1;
  }

  if constexpr (GM == 0) {
    // epilogue: E = exp(S*scale - 1) -> LDS pack -> coalesced fp8 stores,
    // plus per-row sums -> LDS -> one atomicAdd per row per block.
    const float qk = 0.044194173824159216f;
    u8* Pb = (u8*)Dg + (long)b * 16777216;
    __syncthreads();  // all K-loop LDS reads done; reuse lds
    u8* zone = lds + wv * 8192;            // [128 rows][64B], q-xor swizzled
    float* rs = (float*)(lds + 65536);     // [4][256] f32
#pragma unroll
    for (int mi = 0; mi < 8; ++mi) {
      f4v sum4 = (f4v){0.f, 0.f, 0.f, 0.f};
#pragma unroll
      for (int ni = 0; ni < 4; ++ni) {
        int np = kperm(ni * 16 + r16);
        f4v vv = acc[mi][ni];
#pragma unroll
        for (int r2 = 0; r2 < 4; ++r2) {
          float e = __expf(vv[r2] * qk - 1.0f);
          zone[(mi * 16 + q * 4 + r2) * 64 + (np ^ (q << 4))] = f2fp8(e);
          sum4[r2] += e;
        }
      }
#pragma unroll
      for (int o = 8; o; o >>= 1) {
        sum4[0] += __shfl_xor(sum4[0], o, 64);
        sum4[1] += __shfl_xor(sum4[1], o, 64);
        sum4[2] += __shfl_xor(sum4[2], o, 64);
        sum4[3] += __shfl_xor(sum4[3], o, 64);
      }
      if (r16 == 0)
        *(float4*)&rs[wn * 256 + wm * 128 + mi * 16 + q * 4] =
            make_float4(sum4[0], sum4[1], sum4[2], sum4[3]);
    }
    __syncthreads();
#pragma unroll
    for (int i = 0; i < 8; ++i) {
      int zr = i * 16 + (lane >> 2);
      int pc = (lane & 3) ^ ((lane >> 4) & 3);
      uint4 vvv = *(const uint4*)(zone + zr * 64 + pc * 16);
      *(uint4*)(Pb + (long)(bm + wm * 128 + zr) * 4096 + bn + wn * 64 +
                (lane & 3) * 16) = vvv;
    }
    if (t < 256)
      atomicAdd(&rowsum[(long)b * 4096 + bm + t],
                rs[t] + rs[256 + t] + rs[512 + t] + rs[768 + t]);
  } else {
    // epilogue: unnormalized PV partial -> bf16
    u16* D = Dg + (long)b * 8388608 + (long)ks * 2097152;
#pragma unroll
    for (int mi = 0; mi < 8; ++mi) {
      int m0 = bm + wm * 128 + mi * 16 + q * 4;
#pragma unroll
      for (int ni = 0; ni < 4; ++ni) {
        int n = bn + wn * 64 + ni * 16 + r16;
        f4v vv = acc[mi][ni];
#pragma unroll
        for (int r2 = 0; r2 < 4; ++r2)
          D[(long)(m0 + r2) * 512 + n] = f2bf(vv[r2]);
      }
    }
  }
  (void)rowsum;
}

// ---------------- bf16 NT GEMM (FINAL) ------------------------------------
template <int MODE, int BM, int BN>
__global__ __launch_bounds__(256) void gemm_nt(
    const u16* __restrict__ Ag, long sA, const u16* __restrict__ Btg, long sB,
    void* __restrict__ Cg, long sC, int nx, int nyg, int K, long lda, long ldb,
    int N, const float* __restrict__ b0, const float* __restrict__ resid,
    long sR, float scale) {
  constexpr int MI = BM / 32, NI = BN / 32;
  constexpr int AGW = BM / 64, BGW = BN / 64;
  constexpr int NLD = AGW + BGW;
  __shared__ __align__(16) u16 lds_a[3][BM * 32];
  __shared__ __align__(16) u16 lds_b[3][BN * 32];
  const int t = threadIdx.x;
  const int lane = t & 63, wv = t >> 6;
  const int wm = wv >> 1, wn = wv & 1;

  int lin = blockIdx.x;
  int xcd = lin & 7, s = lin >> 3;
  int bn_i = s % nx, t2 = s / nx;
  int bm_i = (t2 % nyg) * 8 + xcd;
  int bz = t2 / nyg;

  const u16* A = Ag + (long)bz * sA;
  const u16* Bt = Btg + (long)bz * sB;
  long c_off = (long)bz * sC;
  const int bm = bm_i * BM, bn = bn_i * BN;

  const u16* aP[AGW];
  const u16* bP[BGW];
#pragma unroll
  for (int j = 0; j < AGW; ++j)
    aP[j] = A + (long)(bm + (wv + j * 4) * 16 + (lane & 15)) * lda +
            (lane >> 4) * 8;
#pragma unroll
  for (int j = 0; j < BGW; ++j)
    bP[j] = Bt + (long)(bn + (wv + j * 4) * 16 + (lane & 15)) * ldb +
            (lane >> 4) * 8;

  auto issue = [&](int buf) {
#pragma unroll
    for (int j = 0; j < AGW; ++j) {
      gload16(aP[j], &lds_a[buf][(wv + j * 4) * 512 + lane * 8]);
      aP[j] += 32;
    }
#pragma unroll
    for (int j = 0; j < BGW; ++j) {
      gload16(bP[j], &lds_b[buf][(wv + j * 4) * 512 + lane * 8]);
      bP[j] += 32;
    }
  };

  f4v acc[MI][NI];
#pragma unroll
  for (int i = 0; i < MI; ++i)
#pragma unroll
    for (int j = 0; j < NI; ++j) acc[i][j] = (f4v){0.f, 0.f, 0.f, 0.f};

  const int NIT = K / 32;
  issue(0);
  issue(1);
  int cur = 0, nxt = 2;
  for (int it = 0; it < NIT; ++it) {
    if (it < NIT - 1)
      asm volatile("s_waitcnt vmcnt(%0)" ::"n"(NLD) : "memory");
    else
      asm volatile("s_waitcnt vmcnt(0)" ::: "memory");
    asm volatile("s_barrier" ::: "memory");
    if (it + 2 < NIT) issue(nxt);

    s8v af[MI], bfr[NI];
#pragma unroll
    for (int mi = 0; mi < MI; ++mi)
      af[mi] = *(const s8v*)&lds_a[cur][((wm * MI + mi) * 64 + lane) * 8];
#pragma unroll
    for (int ni = 0; ni < NI; ++ni)
      bfr[ni] = *(const s8v*)&lds_b[cur][((wn * NI + ni) * 64 + lane) * 8];
#pragma unroll
    for (int mi = 0; mi < MI; ++mi)
#pragma unroll
      for (int ni = 0; ni < NI; ++ni)
        acc[mi][ni] = __builtin_amdgcn_mfma_f32_16x16x32_bf16(
            af[mi], bfr[ni], acc[mi][ni], 0, 0, 0);
    cur = cur == 2 ? 0 : cur + 1;
    nxt = nxt == 2 ? 0 : nxt + 1;
  }

  const int quad = lane >> 4, col = lane & 15;
#pragma unroll
  for (int mi = 0; mi < MI; ++mi) {
#pragma unroll
    for (int ni = 0; ni < NI; ++ni) {
      int n = bn + wn * (BN / 2) + ni * 16 + col;
      int m0 = bm + wm * (BM / 2) + mi * 16 + quad * 4;
      f4v vv = acc[mi][ni];
#pragma unroll
      for (int r2 = 0; r2 < 4; ++r2) {
        int m = m0 + r2;
        float val = vv[r2];
        if constexpr (MODE == MODE_SCALE) val *= scale;
        if constexpr (MODE == MODE_FINAL) {
          val += b0[m] + resid[(long)bz * sR + (long)m * N + n];
          ((float*)Cg)[c_off + (long)m * N + n] = val;
        } else {
          ((u16*)Cg)[c_off + (long)m * N + n] = f2bf(val);
        }
      }
    }
  }
  (void)scale; (void)resid;
}

extern "C" void kernel_launch(void* const* d_in, const int* in_sizes, int n_in,
                              void* d_out, int out_size, void* d_ws,
                              size_t ws_size, hipStream_t stream) {
  const float* x = (const float*)d_in[0];
  const float* gamma = (const float*)d_in[1];
  const float* beta = (const float*)d_in[2];
  const float* wq = (const float*)d_in[3];
  const float* bq = (const float*)d_in[4];
  const float* wk = (const float*)d_in[5];
  const float* bk = (const float*)d_in[6];
  const float* wv = (const float*)d_in[7];
  const float* bv = (const float*)d_in[8];
  const float* wo = (const float*)d_in[9];
  const float* bo = (const float*)d_in[10];

  // ws_size = 256 MiB (observed: harness poison fill writes 262144 KB).
  u8* wsb = (u8*)d_ws;
  u16* hnt = (u16*)wsb;                  // 8M: out_t bf16 (reduce output)
  u8* q8 = wsb + 8388608;                // 4M fp8 [2][4096][512] k-interleaved
  u8* k8 = wsb + 12582912;               // 4M
  u8* v8 = wsb + 16777216;               // 4M fp8 [2][512][4096] k-interleaved
  u16* wob = (u16*)(wsb + 20971520);     // 512K: wo bf16
  u8* w8 = wsb + 21495808;               // 768K: wq/wk/wv fp8 k-ilv [1536][512]
  float2* part = (float2*)(wsb + 23068672);
  float* rowsum = (float*)(wsb + 25165824);  // 32K: [2][4096] f32
  u8* hn8 = wsb + 27262976;              // 4M fp8 [2][4096][512] k-ilv chans
  u8* P8 = wsb + 92274688;               // 32M: [2][4096][4096] fp8 k-ilv
  u16* parts = (u16*)(wsb + 125829120);  // 32M: [2][4][4096][512] bf16

  // stats + weight casts + rowsum zero: one fat kernel
  prep<<<1540, 256, 0, stream>>>(x, wq, wk, wv, wo, part, wob, w8, rowsum);
  // groupnorm apply + transpose -> hn8 fp8
  gn_apply_t<<<dim3(128, 16, 2), 256, 0, stream>>>(x, part, gamma, beta, hn8);

  // fused q/k/v, all-fp8 GEMM: 384 blocks (256x128 over stacked weights)
  gemm_qkv8<<<384, 512, 0, stream>>>(hn8, w8, q8, k8, v8, bq, bk, bv);

  // P8 = exp(scale * q8 k8^T - 1) + rowsum atomics: 512 blocks (256x256)
  gemm8p<0><<<512, 512, 0, stream>>>(q8, k8, (u16*)P8, rowsum);
  // PV fp8 split-K4 (unnormalized), both batches: 256 blocks (256x256)
  gemm8p<1><<<256, 512, 0, stream>>>(P8, v8, parts, rowsum);
  // out_t = (sum of 4 partials) / rowsum, both batches
  reduce_pv4<<<2048, 256, 0, stream>>>(parts, hnt, rowsum);

  // d_out = wo . out_t^T + bo + x: 64x128, nx=32, nyg=1, nz=2 -> 512 blocks
  gemm_nt<MODE_FINAL, 64, 128><<<512, 256, 0, stream>>>(
      wob, 0, hnt, 2097152, d_out, 2097152, 32, 1, 512, 512, 512, 4096, bo,
      x, 2097152, 0.f);

  (void)in_sizes; (void)n_in; (void)out_size; (void)ws_size;
}

// Round 12
// 189.502 us; speedup vs baseline: 1.0673x; 1.0673x over previous
//
#include <hip/hip_runtime.h>

typedef unsigned short u16;
typedef unsigned char u8;
typedef __attribute__((ext_vector_type(8))) short s8v;
typedef __attribute__((ext_vector_type(4))) float f4v;
typedef __attribute__((ext_vector_type(2))) long l2v;

enum { MODE_SCALE = 2, MODE_FINAL = 3 };

__device__ __forceinline__ u16 f2bf(float f) {
  unsigned u = __builtin_bit_cast(unsigned, f);
  u += 0x7fffu + ((u >> 16) & 1u);
  return (u16)(u >> 16);
}
__device__ __forceinline__ float bf2f(u16 h) {
  unsigned u = ((unsigned)h) << 16;
  return __builtin_bit_cast(float, u);
}
__device__ __forceinline__ void gload16(const void* g, void* l) {
  __builtin_amdgcn_global_load_lds(
      (const __attribute__((address_space(1))) unsigned int*)g,
      (__attribute__((address_space(3))) unsigned int*)l, 16, 0, 0);
}
__device__ __forceinline__ unsigned pk4fp8(float a, float b, float c, float d) {
  int lo = __builtin_amdgcn_cvt_pk_fp8_f32(a, b, 0, false);
  return (unsigned)__builtin_amdgcn_cvt_pk_fp8_f32(c, d, lo, true);
}
__device__ __forceinline__ u8 f2fp8(float a) {
  return (u8)(__builtin_amdgcn_cvt_pk_fp8_f32(a, a, 0, false) & 0xff);
}
// k-interleave permutation within each aligned 64B k-group: byte j ->
// ((j>>3)&3)*16 + ((j>>5)&1)*8 + (j&7).  Chunk q (16B) of a row then holds
// [k 8q..8q+7][k 32+8q..32+8q+7] = both MFMA k-slices for lane quad q.
// 4-aligned 4B blocks map to contiguous 4B (j&7 preserved).
__device__ __forceinline__ int kperm(int j) {
  return (j & ~63) | (((j >> 3) & 3) << 4) | (((j >> 5) & 1) << 3) | (j & 7);
}

// ------- prep fat kernel: gn partial stats + weight casts + zeroing -------
// blocks [0,512):    gn_stats (x partial sums, 2 channels/block)
// blocks [512,1536): wq/wk/wv -> fp8 k-ilv (w8); wo -> bf16 (wob)
// blocks [1536,1540): zero rowsum (2x4096 f32)
__global__ __launch_bounds__(256) void prep(
    const float* __restrict__ x, const float* __restrict__ w0,
    const float* __restrict__ w1, const float* __restrict__ w2,
    const float* __restrict__ w3, float2* __restrict__ part,
    u16* __restrict__ wob, u8* __restrict__ w8,
    float* __restrict__ rowsum) {
  const int bid = blockIdx.x;
  const int t = threadIdx.x;
  if (bid < 512) {
    const float4* p4 = (const float4*)(x + (long)bid * 8192);
    float s = 0.f, q = 0.f;
#pragma unroll
    for (int j = 0; j < 8; ++j) {
      float4 f = p4[t + 256 * j];
      s += f.x + f.y + f.z + f.w;
      q += f.x * f.x + f.y * f.y + f.z * f.z + f.w * f.w;
    }
#pragma unroll
    for (int o = 32; o; o >>= 1) {
      s += __shfl_xor(s, o, 64);
      q += __shfl_xor(q, o, 64);
    }
    __shared__ float rs[4], rq[4];
    int lane = t & 63, wv = t >> 6;
    if (lane == 0) { rs[wv] = s; rq[wv] = q; }
    __syncthreads();
    if (t == 0)
      part[bid] = make_float2(rs[0] + rs[1] + rs[2] + rs[3],
                              rq[0] + rq[1] + rq[2] + rq[3]);
  } else if (bid < 1536) {
    int wb = bid - 512;
    int which = wb >> 8;
    const float* w = which == 0 ? w0 : which == 1 ? w1 : which == 2 ? w2 : w3;
    int i = ((wb & 255) * 256 + t) * 4;
    float4 f = *(const float4*)(w + i);
    if (which == 3) {
      ushort4 r;
      r.x = f2bf(f.x); r.y = f2bf(f.y); r.z = f2bf(f.z); r.w = f2bf(f.w);
      *(ushort4*)(wob + i) = r;
    } else {
      // fp8 k-interleaved on the in-channel (col) axis
      *(unsigned*)(w8 + which * 262144 + (i & ~511) + kperm(i & 511)) =
          pk4fp8(f.x, f.y, f.z, f.w);
    }
  } else {
    int idx = (bid - 1536) * 256 + t;
    float4 z = {0.f, 0.f, 0.f, 0.f};
    *(float4*)(rowsum + idx * 8) = z;
    *(float4*)(rowsum + idx * 8 + 4) = z;
  }
}

// ------- apply groupnorm + transpose -> hn8 fp8 (k-interleaved chans) -----
__global__ __launch_bounds__(256) void gn_apply_t(const float* __restrict__ x,
                                                  const float2* __restrict__ part,
                                                  const float* __restrict__ gamma,
                                                  const float* __restrict__ beta,
                                                  u8* __restrict__ hn8) {
  int p0 = blockIdx.x * 32, c0 = blockIdx.y * 32, b = blockIdx.z;
  __shared__ float tile[32][33];
  __shared__ float2 ABs[32];
  int t = threadIdx.x;
  if (t < 32) {
    int c = c0 + t;
    int g = (b * 512 + c) >> 4;  // global 16-channel group
    float s = 0.f, q = 0.f;
#pragma unroll
    for (int j = 0; j < 8; ++j) {
      float2 pp = part[g * 8 + j];
      s += pp.x; q += pp.y;
    }
    float mean = s * (1.0f / 65536.0f);
    float var = q * (1.0f / 65536.0f) - mean * mean;
    float a = gamma[c] * rsqrtf(var + 1e-6f);
    ABs[t] = make_float2(a, beta[c] - mean * a);
  }
  const float* xb = x + (long)b * 2097152;
#pragma unroll
  for (int j = 0; j < 4; ++j) {
    int lc = (t >> 5) + j * 8, lp = t & 31;
    tile[lc][lp] = xb[(long)(c0 + lc) * 4096 + p0 + lp];
  }
  __syncthreads();
#pragma unroll
  for (int j = 0; j < 4; ++j) {
    int lp = (t >> 5) + j * 8, lc = t & 31;
    float2 ab = ABs[lc];
    float val = tile[lc][lp] * ab.x + ab.y;
    hn8[(long)b * 2097152 + (long)(p0 + lp) * 512 + kperm(c0 + lc)] =
        f2fp8(val);
  }
}

// ------- split-K4 reduce + rowsum normalize -> out_t (bf16) ---------------
__global__ __launch_bounds__(256) void reduce_pv4(const u16* __restrict__ parts,
                                                  u16* __restrict__ out,
                                                  const float* __restrict__ rowsum) {
  long i = ((long)blockIdx.x * 256 + threadIdx.x) * 8;  // [0, 4194304)
  long b = i >> 21, off = i & 2097151;
  const u16* base = parts + b * 8388608 + off;
  float inv = 1.0f / rowsum[b * 4096 + (off >> 9)];
  s8v a = *(const s8v*)(base);
  s8v bb = *(const s8v*)(base + 2097152);
  s8v c = *(const s8v*)(base + 4194304);
  s8v d = *(const s8v*)(base + 6291456);
  s8v o;
#pragma unroll
  for (int j = 0; j < 8; ++j)
    o[j] = (short)f2bf((bf2f((u16)a[j]) + bf2f((u16)bb[j]) + bf2f((u16)c[j]) +
                        bf2f((u16)d[j])) * inv);
  *(s8v*)(out + i) = o;
}

// ------- fused QKV GEMM, all-fp8 (hn8 . w8^T), 256x128 1-barrier loop -----
__global__ __launch_bounds__(512, 4) void gemm_qkv8(
    const u8* __restrict__ hn8, const u8* __restrict__ w8,
    u8* __restrict__ q8, u8* __restrict__ k8, u8* __restrict__ v8,
    const float* __restrict__ bq, const float* __restrict__ bk,
    const float* __restrict__ bv) {
  constexpr int NKT = 8;
  constexpr long ld = 512;
  constexpr long ha = 128 * ld;
  constexpr int BUF = 24576;
  __shared__ __align__(16) u8 lds[73728];

  const int t = threadIdx.x;
  const int lane = t & 63, wv = t >> 6;
  const int wm = wv >> 1, wn = wv & 1;

  int lin = blockIdx.x;
  int xcd = lin & 7, s = lin >> 3;          // s in [0,48)
  int bn_i = s % 12, rest = s / 12;         // rest in [0,4)
  int bm_i = (rest & 1) * 8 + xcd;
  int b = rest >> 1;
  const int bm = bm_i * 256, bn = bn_i * 128;

  const u8* A = hn8 + (long)b * 2097152;
  const int tchunk = ((t & 3) ^ ((t >> 3) & 3)) * 16;
  const u8* pA0 = A + (long)(bm + (t >> 2)) * ld + tchunk;
  const u8* pB0 = w8 + (long)(bn + (t >> 2)) * ld + tchunk;

  const int r16 = lane & 15, q = lane >> 4;
  const int swz = (r16 >> 1) & 3;
  const int caq = (q ^ swz) * 16;
  const int aRow = (wm * 64 + r16) * 64;
  const int bRow = 16384 + (wn * 64 + r16) * 64;

  f4v acc[4][4];
#pragma unroll
  for (int i = 0; i < 4; ++i)
#pragma unroll
    for (int j = 0; j < 4; ++j) acc[i][j] = (f4v){0.f, 0.f, 0.f, 0.f};

#pragma unroll
  for (int T = 0; T < 2; ++T) {
    gload16(pA0 + T * 64, &lds[T * BUF + t * 16]);
    gload16(pA0 + ha + T * 64, &lds[T * BUF + 8192 + t * 16]);
    gload16(pB0 + T * 64, &lds[T * BUF + 16384 + t * 16]);
  }
  asm volatile("s_waitcnt vmcnt(3)" ::: "memory");
  asm volatile("s_barrier" ::: "memory");

  int cur = 0, nbuf = 2;
  const u8* pA = pA0 + 128;
  const u8* pB = pB0 + 128;
  for (int kt = 0; kt < NKT; ++kt) {
    const u8* LA = &lds[cur * BUF];
    u8* SB = &lds[nbuf * BUF];
    const bool st = kt <= NKT - 3;

    l2v af[4], bfv[4];
#pragma unroll
    for (int mi = 0; mi < 4; ++mi)
      af[mi] = *(const l2v*)(LA + aRow + mi * 1024 + caq);
#pragma unroll
    for (int ni = 0; ni < 4; ++ni)
      bfv[ni] = *(const l2v*)(LA + bRow + ni * 1024 + caq);

    if (st) gload16(pA, SB + t * 16);
    __builtin_amdgcn_s_setprio(1);
#pragma unroll
    for (int mi = 0; mi < 2; ++mi)
#pragma unroll
      for (int ni = 0; ni < 4; ++ni) {
        acc[mi][ni] = __builtin_amdgcn_mfma_f32_16x16x32_fp8_fp8(
            af[mi][0], bfv[ni][0], acc[mi][ni], 0, 0, 0);
        acc[mi][ni] = __builtin_amdgcn_mfma_f32_16x16x32_fp8_fp8(
            af[mi][1], bfv[ni][1], acc[mi][ni], 0, 0, 0);
      }
    __builtin_amdgcn_s_setprio(0);
    if (st) gload16(pA + ha, SB + 8192 + t * 16);
    __builtin_amdgcn_s_setprio(1);
#pragma unroll
    for (int mi = 2; mi < 4; ++mi)
#pragma unroll
      for (int ni = 0; ni < 4; ++ni) {
        acc[mi][ni] = __builtin_amdgcn_mfma_f32_16x16x32_fp8_fp8(
            af[mi][0], bfv[ni][0], acc[mi][ni], 0, 0, 0);
        acc[mi][ni] = __builtin_amdgcn_mfma_f32_16x16x32_fp8_fp8(
            af[mi][1], bfv[ni][1], acc[mi][ni], 0, 0, 0);
      }
    __builtin_amdgcn_s_setprio(0);
    if (st) gload16(pB, SB + 16384 + t * 16);

    if (kt < NKT - 1) {
      if (st)
        asm volatile("s_waitcnt vmcnt(3)" ::: "memory");
      else
        asm volatile("s_waitcnt vmcnt(0)" ::: "memory");
      asm volatile("s_barrier" ::: "memory");
    }
    pA += 64;
    pB += 64;
    cur = cur == 2 ? 0 : cur + 1;
    nbuf = nbuf == 2 ? 0 : nbuf + 1;
  }

  const int w = bn >> 9;  // block-uniform: 128-tile within one 512 window
  const float* bias = w == 0 ? bq : w == 1 ? bk : bv;
  u8* qkdst = (w == 0 ? q8 : k8) + (long)b * 2097152;
  u8* vdst = v8 + (long)b * 2097152;
#pragma unroll
  for (int mi = 0; mi < 4; ++mi) {
    int m0 = bm + wm * 64 + mi * 16 + q * 4;
#pragma unroll
    for (int ni = 0; ni < 4; ++ni) {
      int n = bn + wn * 64 + ni * 16 + r16;
      int o = n & 511;
      f4v vvv = acc[mi][ni];
      float bsv = bias[o];
      if (w == 2) {
        // v8[o][m]: pixel axis kperm'd (PV's K); m0%8 in {0,4}
        *(unsigned*)&vdst[(long)o * 4096 + kperm(m0)] =
            pk4fp8(vvv[0] + bsv, vvv[1] + bsv, vvv[2] + bsv, vvv[3] + bsv);
      } else {
        int op = kperm(o);
#pragma unroll
        for (int r2 = 0; r2 < 4; ++r2)
          qkdst[(long)(m0 + r2) * 512 + op] = f2fp8(vvv[r2] + bsv);
      }
    }
  }
}

// ---------------- fp8 256x128-tile GEMM, 1 barrier / K-tile ---------------
// GM==0: P8 = exp(scale*q8.k8^T - 1) fp8 k-ilv + rowsum atomics.
//        M=4096 N=4096 K=512.                        grid 1024, 512 thr
// GM==1: parts = P8 . v8^T (unnormalized, split-K4)  grid 512, 512 thr
// 256x128 tile, BK=64, 8 waves, 3 LDS buffers of 24KB (72KB -> 2 blocks/CU).
// Inputs k-interleaved (kperm): one ds_read_b128 per fragment pair; chunk
// swizzle (r16>>1)&3 keeps reads bank-conflict-free.  One s_barrier per
// K-tile; counted vmcnt(3) gate (3 staging loads/thread/tile).
// NOTE: body/signature must stay EXACTLY this r6-verified form.  History:
// r5 finisher graft -> VGPR=64 acc spill (5.3x); r8 (512,2) reg-pipeline ->
// 1 blk/CU + 1.05M read/write-overlap LDS conflicts; r9 split-K2 -> lost
// 2-blk/CU; r11 4-phase 256^2 -> same 1.05M conflicts, 27.8% MfmaUtil.
// Four schedule variants span 27-31% MfmaUtil: this family's floor is the
// barrier-coupled LDS+staging pipeline; only 2-blk/CU TLP mitigates it.
template <int GM>
__global__ __launch_bounds__(512, 4) void gemm8p(const u8* __restrict__ Ag,
                                                 const u8* __restrict__ Bg,
                                                 u16* __restrict__ Dg,
                                                 float* __restrict__ rowsum) {
  constexpr int NKT = GM == 0 ? 8 : 16;
  constexpr long ld = GM == 0 ? 512 : 4096;  // A and B K-stride (bytes)
  constexpr int nx = GM == 0 ? 32 : 4;       // N tiles (128-wide)
  constexpr long ha = 128 * ld;              // A half-tile (128 rows)
  constexpr int BUF = 24576;
  __shared__ __align__(16) u8 lds[73728];

  const int t = threadIdx.x;
  const int lane = t & 63, wv = t >> 6;
  const int wm = wv >> 1, wn = wv & 1;

  int lin = blockIdx.x;
  int xcd = lin & 7, s = lin >> 3;
  int bn_i = s % nx, rest = s / nx;
  int bm_i = (rest & 1) * 8 + xcd, rest2 = rest >> 1;
  int ks = 0, b;
  if constexpr (GM == 1) {
    ks = rest2 & 3;
    b = rest2 >> 2;
  } else {
    b = rest2;
  }
  const int bm = bm_i * 256, bn = bn_i * 128;

  const u8* A = Ag + (long)b * (GM == 0 ? 2097152 : 16777216);
  const u8* B = Bg + (long)b * 2097152;
  const long k0 = GM == 1 ? (long)ks * 1024 : 0;

  // staging: thread t covers row (t>>2), 16B chunk (t&3); source chunk
  // pre-swizzled so LDS holds row[chunk ^ ((row>>1)&3)].
  const int tchunk = ((t & 3) ^ ((t >> 3) & 3)) * 16;
  const u8* pA0 = A + (long)(bm + (t >> 2)) * ld + k0 + tchunk;
  const u8* pB0 = B + (long)(bn + (t >> 2)) * ld + k0 + tchunk;

  // per-lane read constants: fragment row = lane&15, chunk = lane>>4
  const int r16 = lane & 15, q = lane >> 4;
  const int swz = (r16 >> 1) & 3;
  const int caq = (q ^ swz) * 16;
  const int aRow = (wm * 64 + r16) * 64;           // A zone [0,16384)
  const int bRow = 16384 + (wn * 64 + r16) * 64;   // B zone [16384,24576)

  f4v acc[4][4];
#pragma unroll
  for (int i = 0; i < 4; ++i)
#pragma unroll
    for (int j = 0; j < 4; ++j) acc[i][j] = (f4v){0.f, 0.f, 0.f, 0.f};

  // prologue: stage K-tiles 0,1 into bufs 0,1 (6 loads/thread)
#pragma unroll
  for (int T = 0; T < 2; ++T) {
    gload16(pA0 + T * 64, &lds[T * BUF + t * 16]);
    gload16(pA0 + ha + T * 64, &lds[T * BUF + 8192 + t * 16]);
    gload16(pB0 + T * 64, &lds[T * BUF + 16384 + t * 16]);
  }
  asm volatile("s_waitcnt vmcnt(3)" ::: "memory");  // tile 0 landed
  asm volatile("s_barrier" ::: "memory");

  int cur = 0, nbuf = 2;
  const u8* pA = pA0 + 128;  // tile kt+2 source
  const u8* pB = pB0 + 128;
  for (int kt = 0; kt < NKT; ++kt) {
    const u8* LA = &lds[cur * BUF];
    u8* SB = &lds[nbuf * BUF];
    const bool st = kt <= NKT - 3;

    l2v af[4], bfv[4];
#pragma unroll
    for (int mi = 0; mi < 4; ++mi)
      af[mi] = *(const l2v*)(LA + aRow + mi * 1024 + caq);
#pragma unroll
    for (int ni = 0; ni < 4; ++ni)
      bfv[ni] = *(const l2v*)(LA + bRow + ni * 1024 + caq);

    if (st) gload16(pA, SB + t * 16);
    __builtin_amdgcn_s_setprio(1);
#pragma unroll
    for (int mi = 0; mi < 2; ++mi)
#pragma unroll
      for (int ni = 0; ni < 4; ++ni) {
        acc[mi][ni] = __builtin_amdgcn_mfma_f32_16x16x32_fp8_fp8(
            af[mi][0], bfv[ni][0], acc[mi][ni], 0, 0, 0);
        acc[mi][ni] = __builtin_amdgcn_mfma_f32_16x16x32_fp8_fp8(
            af[mi][1], bfv[ni][1], acc[mi][ni], 0, 0, 0);
      }
    __builtin_amdgcn_s_setprio(0);
    if (st) gload16(pA + ha, SB + 8192 + t * 16);
    __builtin_amdgcn_s_setprio(1);
#pragma unroll
    for (int mi = 2; mi < 4; ++mi)
#pragma unroll
      for (int ni = 0; ni < 4; ++ni) {
        acc[mi][ni] = __builtin_amdgcn_mfma_f32_16x16x32_fp8_fp8(
            af[mi][0], bfv[ni][0], acc[mi][ni], 0, 0, 0);
        acc[mi][ni] = __builtin_amdgcn_mfma_f32_16x16x32_fp8_fp8(
            af[mi][1], bfv[ni][1], acc[mi][ni], 0, 0, 0);
      }
    __builtin_amdgcn_s_setprio(0);
    if (st) gload16(pB, SB + 16384 + t * 16);

    if (kt < NKT - 1) {
      if (st)
        asm volatile("s_waitcnt vmcnt(3)" ::: "memory");
      else
        asm volatile("s_waitcnt vmcnt(0)" ::: "memory");
      asm volatile("s_barrier" ::: "memory");
    }
    pA += 64;
    pB += 64;
    cur = cur == 2 ? 0 : cur + 1;
    nbuf = nbuf == 2 ? 0 : nbuf + 1;
  }

  if constexpr (GM == 0) {
    // epilogue: E = exp(S*scale - 1) -> LDS pack -> coalesced fp8 stores,
    // plus per-row sums -> LDS -> one atomicAdd per row per block.
    const float qk = 0.044194173824159216f;
    u8* Pb = (u8*)Dg + (long)b * 16777216;
    __syncthreads();  // all K-loop LDS reads done; reuse lds
    u8* zone = lds + wv * 4096;            // [64 rows][64B], q-xor swizzled
    float* rs = (float*)(lds + 32768);     // [2][256] f32
#pragma unroll
    for (int mi = 0; mi < 4; ++mi) {
      f4v sum4 = (f4v){0.f, 0.f, 0.f, 0.f};
#pragma unroll
      for (int ni = 0; ni < 4; ++ni) {
        int np = kperm(ni * 16 + r16);
        f4v vv = acc[mi][ni];
#pragma unroll
        for (int r2 = 0; r2 < 4; ++r2) {
          float e = __expf(vv[r2] * qk - 1.0f);
          zone[(mi * 16 + q * 4 + r2) * 64 + (np ^ (q << 4))] = f2fp8(e);
          sum4[r2] += e;
        }
      }
#pragma unroll
      for (int o = 8; o; o >>= 1) {
        sum4[0] += __shfl_xor(sum4[0], o, 64);
        sum4[1] += __shfl_xor(sum4[1], o, 64);
        sum4[2] += __shfl_xor(sum4[2], o, 64);
        sum4[3] += __shfl_xor(sum4[3], o, 64);
      }
      if (r16 == 0)
        *(float4*)&rs[wn * 256 + wm * 64 + mi * 16 + q * 4] =
            make_float4(sum4[0], sum4[1], sum4[2], sum4[3]);
    }
    __syncthreads();
#pragma unroll
    for (int i = 0; i < 4; ++i) {
      int zr = i * 16 + (lane >> 2);
      int pc = (lane & 3) ^ ((lane >> 4) & 3);
      uint4 vvv = *(const uint4*)(zone + zr * 64 + pc * 16);
      *(uint4*)(Pb + (long)(bm + wm * 64 + zr) * 4096 + bn + wn * 64 +
                (lane & 3) * 16) = vvv;
    }
    if (t < 256)
      atomicAdd(&rowsum[(long)b * 4096 + bm + t], rs[t] + rs[256 + t]);
  } else {
    // epilogue: unnormalized PV partial -> bf16
    u16* D = Dg + (long)b * 8388608 + (long)ks * 2097152;
#pragma unroll
    for (int mi = 0; mi < 4; ++mi) {
      int m0 = bm + wm * 64 + mi * 16 + q * 4;
#pragma unroll
      for (int ni = 0; ni < 4; ++ni) {
        int n = bn + wn * 64 + ni * 16 + r16;
        f4v vv = acc[mi][ni];
#pragma unroll
        for (int r2 = 0; r2 < 4; ++r2)
          D[(long)(m0 + r2) * 512 + n] = f2bf(vv[r2]);
      }
    }
  }
  (void)rowsum;
}

// ---------------- bf16 NT GEMM (FINAL) ------------------------------------
template <int MODE, int BM, int BN>
__global__ __launch_bounds__(256) void gemm_nt(
    const u16* __restrict__ Ag, long sA, const u16* __restrict__ Btg, long sB,
    void* __restrict__ Cg, long sC, int nx, int nyg, int K, long lda, long ldb,
    int N, const float* __restrict__ b0, const float* __restrict__ resid,
    long sR, float scale) {
  constexpr int MI = BM / 32, NI = BN / 32;
  constexpr int AGW = BM / 64, BGW = BN / 64;
  constexpr int NLD = AGW + BGW;
  __shared__ __align__(16) u16 lds_a[3][BM * 32];
  __shared__ __align__(16) u16 lds_b[3][BN * 32];
  const int t = threadIdx.x;
  const int lane = t & 63, wv = t >> 6;
  const int wm = wv >> 1, wn = wv & 1;

  int lin = blockIdx.x;
  int xcd = lin & 7, s = lin >> 3;
  int bn_i = s % nx, t2 = s / nx;
  int bm_i = (t2 % nyg) * 8 + xcd;
  int bz = t2 / nyg;

  const u16* A = Ag + (long)bz * sA;
  const u16* Bt = Btg + (long)bz * sB;
  long c_off = (long)bz * sC;
  const int bm = bm_i * BM, bn = bn_i * BN;

  const u16* aP[AGW];
  const u16* bP[BGW];
#pragma unroll
  for (int j = 0; j < AGW; ++j)
    aP[j] = A + (long)(bm + (wv + j * 4) * 16 + (lane & 15)) * lda +
            (lane >> 4) * 8;
#pragma unroll
  for (int j = 0; j < BGW; ++j)
    bP[j] = Bt + (long)(bn + (wv + j * 4) * 16 + (lane & 15)) * ldb +
            (lane >> 4) * 8;

  auto issue = [&](int buf) {
#pragma unroll
    for (int j = 0; j < AGW; ++j) {
      gload16(aP[j], &lds_a[buf][(wv + j * 4) * 512 + lane * 8]);
      aP[j] += 32;
    }
#pragma unroll
    for (int j = 0; j < BGW; ++j) {
      gload16(bP[j], &lds_b[buf][(wv + j * 4) * 512 + lane * 8]);
      bP[j] += 32;
    }
  };

  f4v acc[MI][NI];
#pragma unroll
  for (int i = 0; i < MI; ++i)
#pragma unroll
    for (int j = 0; j < NI; ++j) acc[i][j] = (f4v){0.f, 0.f, 0.f, 0.f};

  const int NIT = K / 32;
  issue(0);
  issue(1);
  int cur = 0, nxt = 2;
  for (int it = 0; it < NIT; ++it) {
    if (it < NIT - 1)
      asm volatile("s_waitcnt vmcnt(%0)" ::"n"(NLD) : "memory");
    else
      asm volatile("s_waitcnt vmcnt(0)" ::: "memory");
    asm volatile("s_barrier" ::: "memory");
    if (it + 2 < NIT) issue(nxt);

    s8v af[MI], bfr[NI];
#pragma unroll
    for (int mi = 0; mi < MI; ++mi)
      af[mi] = *(const s8v*)&lds_a[cur][((wm * MI + mi) * 64 + lane) * 8];
#pragma unroll
    for (int ni = 0; ni < NI; ++ni)
      bfr[ni] = *(const s8v*)&lds_b[cur][((wn * NI + ni) * 64 + lane) * 8];
#pragma unroll
    for (int mi = 0; mi < MI; ++mi)
#pragma unroll
      for (int ni = 0; ni < NI; ++ni)
        acc[mi][ni] = __builtin_amdgcn_mfma_f32_16x16x32_bf16(
            af[mi], bfr[ni], acc[mi][ni], 0, 0, 0);
    cur = cur == 2 ? 0 : cur + 1;
    nxt = nxt == 2 ? 0 : nxt + 1;
  }

  const int quad = lane >> 4, col = lane & 15;
#pragma unroll
  for (int mi = 0; mi < MI; ++mi) {
#pragma unroll
    for (int ni = 0; ni < NI; ++ni) {
      int n = bn + wn * (BN / 2) + ni * 16 + col;
      int m0 = bm + wm * (BM / 2) + mi * 16 + quad * 4;
      f4v vv = acc[mi][ni];
#pragma unroll
      for (int r2 = 0; r2 < 4; ++r2) {
        int m = m0 + r2;
        float val = vv[r2];
        if constexpr (MODE == MODE_SCALE) val *= scale;
        if constexpr (MODE == MODE_FINAL) {
          val += b0[m] + resid[(long)bz * sR + (long)m * N + n];
          ((float*)Cg)[c_off + (long)m * N + n] = val;
        } else {
          ((u16*)Cg)[c_off + (long)m * N + n] = f2bf(val);
        }
      }
    }
  }
  (void)scale; (void)resid;
}

extern "C" void kernel_launch(void* const* d_in, const int* in_sizes, int n_in,
                              void* d_out, int out_size, void* d_ws,
                              size_t ws_size, hipStream_t stream) {
  const float* x = (const float*)d_in[0];
  const float* gamma = (const float*)d_in[1];
  const float* beta = (const float*)d_in[2];
  const float* wq = (const float*)d_in[3];
  const float* bq = (const float*)d_in[4];
  const float* wk = (const float*)d_in[5];
  const float* bk = (const float*)d_in[6];
  const float* wv = (const float*)d_in[7];
  const float* bv = (const float*)d_in[8];
  const float* wo = (const float*)d_in[9];
  const float* bo = (const float*)d_in[10];

  // ws_size = 256 MiB (observed: harness poison fill writes 262144 KB).
  u8* wsb = (u8*)d_ws;
  u16* hnt = (u16*)wsb;                  // 8M: out_t bf16 (reduce output)
  u8* q8 = wsb + 8388608;                // 4M fp8 [2][4096][512] k-interleaved
  u8* k8 = wsb + 12582912;               // 4M
  u8* v8 = wsb + 16777216;               // 4M fp8 [2][512][4096] k-interleaved
  u16* wob = (u16*)(wsb + 20971520);     // 512K: wo bf16
  u8* w8 = wsb + 21495808;               // 768K: wq/wk/wv fp8 k-ilv [1536][512]
  float2* part = (float2*)(wsb + 23068672);
  float* rowsum = (float*)(wsb + 25165824);  // 32K: [2][4096] f32
  u8* hn8 = wsb + 27262976;              // 4M fp8 [2][4096][512] k-ilv chans
  u8* P8 = wsb + 92274688;               // 32M: [2][4096][4096] fp8 k-ilv
  u16* parts = (u16*)(wsb + 125829120);  // 32M: [2][4][4096][512] bf16

  // stats + weight casts + rowsum zero: one fat kernel
  prep<<<1540, 256, 0, stream>>>(x, wq, wk, wv, wo, part, wob, w8, rowsum);
  // groupnorm apply + transpose -> hn8 fp8
  gn_apply_t<<<dim3(128, 16, 2), 256, 0, stream>>>(x, part, gamma, beta, hn8);

  // fused q/k/v, all-fp8 GEMM: 384 blocks (256x128 over stacked weights)
  gemm_qkv8<<<384, 512, 0, stream>>>(hn8, w8, q8, k8, v8, bq, bk, bv);

  // P8 = exp(scale * q8 k8^T - 1) + rowsum atomics: 1024 blocks (256x128)
  gemm8p<0><<<1024, 512, 0, stream>>>(q8, k8, (u16*)P8, rowsum);
  // PV fp8 split-K4 (unnormalized), both batches: 512 blocks (256x128)
  gemm8p<1><<<512, 512, 0, stream>>>(P8, v8, parts, rowsum);
  // out_t = (sum of 4 partials) / rowsum, both batches
  reduce_pv4<<<2048, 256, 0, stream>>>(parts, hnt, rowsum);

  // d_out = wo . out_t^T + bo + x: 64x128, nx=32, nyg=1, nz=2 -> 512 blocks
  gemm_nt<MODE_FINAL, 64, 128><<<512, 256, 0, stream>>>(
      wob, 0, hnt, 2097152, d_out, 2097152, 32, 1, 512, 512, 512, 4096, bo,
      x, 2097152, 0.f);

  (void)in_sizes; (void)n_in; (void)out_size; (void)ws_size;
}